// Round 14
// baseline (1197.540 us; speedup 1.0000x reference)
//
#include <hip/hip_runtime.h>

typedef float  f32x4  __attribute__((ext_vector_type(4)));
typedef short  s16x8  __attribute__((ext_vector_type(8)));
typedef short  s16x4  __attribute__((ext_vector_type(4)));
typedef _Float16 f16;

namespace {
constexpr int NN = 127, IDIM = 300, HD = 150;
constexpr int GNT = 640;             // gemm: 10 waves; wave wv owns col-triple wv
constexpr int XSTR = 324;            // A stride (shorts): 162 dw -> 2-way banks (free)
constexpr int BCS  = 36;             // B col stride (shorts): 18 dw -> 16-bank spread
constexpr int SLAB_SH = 17408;       // 480*36=17280 + pad = 34 KiB
constexpr int SCH = 34;              // 1-KiB staging chunks per slab
constexpr int A_SH = 64 * XSTR;      // 20736 shorts
constexpr int GEMM_LDS = (A_SH + SLAB_SH) * 2;   // 76,288 B -> 2 blocks/CU
constexpr int LNT = 320;
constexpr int CSTR = 168;            // light chs/hts stride

constexpr int W_SH = 10 * SLAB_SH;   // [kc][col][36]
constexpr int U_SH = 480 * 160;      // plain [col][k]
constexpr int F_SH = 160 * 160;

// ws rings: c f16 [4096][126][152] | hb bf16 [4096][127][152] | iuo f16 [4096][63][456] | slabs
constexpr size_t C_N   = (size_t)4096 * 126 * 152;
constexpr size_t HB_N  = (size_t)4096 * 127 * 152;
constexpr size_t IUO_N = (size_t)4096 * 63 * 456;

__device__ __forceinline__ short f2bf(float f) {
    union { __bf16 b; short s; } u; u.b = (__bf16)f; return u.s;
}
__device__ __forceinline__ float bf2f(short s) {
    union { float f; unsigned u; } v; v.u = ((unsigned)(unsigned short)s) << 16; return v.f;
}
__device__ __forceinline__ float sig_(float x)  { return 1.0f / (1.0f + __expf(-x)); }
__device__ __forceinline__ float tanh_(float x) { float e = __expf(2.0f * x); return 1.0f - 2.0f / (e + 1.0f); }
__device__ __forceinline__ s16x4 cvt4(float a,float b,float c,float d) {
    return s16x4{ f2bf(a), f2bf(b), f2bf(c), f2bf(d) };
}
__device__ __forceinline__ s16x8 cat(s16x4 lo, s16x4 hi) {
    return __builtin_shufflevector(lo, hi, 0,1,2,3,4,5,6,7);
}
__device__ __forceinline__ f32x4 MFMA(s16x8 a, s16x8 b, f32x4 c) {
    return __builtin_amdgcn_mfma_f32_16x16x32_bf16(a, b, c, 0, 0, 0);
}
typedef const __attribute__((address_space(1))) unsigned int* gp_t;
typedef __attribute__((address_space(3))) unsigned int* lp_t;
__device__ __forceinline__ void stage_slab(const short* g, short* l, int wv, int ln) {
    const char* gb = (const char*)g;
    char* lb = (char*)l;
    for (int c = wv; c < SCH; c += 10)
        __builtin_amdgcn_global_load_lds((gp_t)(gb + c * 1024 + ln * 16),
                                         (lp_t)(lb + c * 1024 + ln * 16), 16, 0, 0);
}
} // namespace

// -------- one-time weight prep: W -> 10 K-chunk slabs [480][36]; U,F plain [col][160] --------
__global__ __launch_bounds__(256)
void prep_w(const float* __restrict__ Wiuo, const float* __restrict__ Uiuo,
            const float* __restrict__ Ufw, short* __restrict__ dst) {
    int i = blockIdx.x * 256 + threadIdx.x;
    short v = 0;
    if (i < W_SH) {
        int kc = i / SLAB_SH, r = i - kc * SLAB_SH;
        if (r < 480 * BCS) {
            int col = r / BCS, j = r - col * BCS;
            int g = col / 160, cp = col - g * 160, k = kc * 32 + j;
            if (cp < HD && j < 32 && k < IDIM) v = f2bf(Wiuo[(size_t)(g*HD + cp)*IDIM + k]);
        }
        dst[i] = v;
    } else if (i < W_SH + U_SH) {
        int q = i - W_SH;
        int col = q / 160, k = q - col * 160;
        int g = col / 160, cp = col - g * 160;
        if (cp < HD && k < HD) v = f2bf(Uiuo[(size_t)(g*HD + cp)*HD + k]);
        dst[i] = v;
    } else if (i < W_SH + U_SH + F_SH) {
        int q = i - W_SH - U_SH;
        int col = q / 160, k = q - col * 160;
        if (col < HD && k < HD) v = f2bf(Ufw[(size_t)col*HD + k]);
        dst[i] = v;
    }
}

// -------- merged projection GEMM: A prologue-staged, SINGLE B buffer, 2 blocks/CU --------
// Per chunk: barrier -> compute(kc) -> barrier -> issue DMA(kc+1). DMA is exposed within
// the block but the co-resident block's compute fills the CU (m114 cross-block overlap).
// MFMA maps: A row=lane&15, B col=lane&15 (shared lane->k); C/D col=lane&15, row=4*(lane>>4)+reg.
__global__ __launch_bounds__(GNT, 5)
void big_gemm(const float* __restrict__ x, const short* __restrict__ Wsl,
              const float* __restrict__ biuo, float* __restrict__ h_all,
              f16* __restrict__ c_ring, short* __restrict__ hb,
              f16* __restrict__ iuo_all)
{
    extern __shared__ short smem[];
    short* As = smem;                // [64][324]
    short* Bs = smem + A_SH;         // [480][36] single buffer

    const int t = threadIdx.x;
    const int wv = t >> 6, ln = t & 63, l15 = ln & 15, kg = ln >> 4;
    const int kg8 = kg * 8;
    const int row0 = blockIdx.x * 64;

    int d = 6;
    #pragma unroll
    for (int dd = 0; dd <= 5; ++dd)
        if (row0 >= 4096 * (128 - (2 << dd))) { d = dd; break; }
    const int base = 4096 * (128 - (2 << d));
    const int lg = d, mask = (1 << lg) - 1, start = (1 << lg) - 1;
    const int local0 = row0 - base;

    // prologue: issue B slab 0, stage A fully (coalesced float4 -> bf16 quads)
    stage_slab(Wsl, Bs, wv, ln);
    {
        constexpr int NQ = XSTR / 4;     // 81 quads/row
        for (int u = t; u < 64 * NQ; u += GNT) {
            int row = u / NQ, q = u - row * NQ;
            int k0 = q * 4;
            int lcl = local0 + row, b = lcl >> lg, s = lcl & mask;
            s16x4 v = {0,0,0,0};
            if (k0 + 4 <= IDIM) {
                float4 f = *(const float4*)(x + ((size_t)b * NN + start + s) * IDIM + k0);
                v = cvt4(f.x, f.y, f.z, f.w);
            }
            *(s16x4*)&As[row * XSTR + k0] = v;
        }
    }

    f32x4 acc[4][3] = {};            // [row-tile mt][gate g]
    #pragma unroll
    for (int kc = 0; kc < 10; ++kc) {
        __syncthreads();             // slab kc landed (vmcnt drain) + A visible (kc=0)

        s16x8 a[4];
        #pragma unroll
        for (int mt = 0; mt < 4; ++mt) {
            const short* p = &As[(16*mt + l15) * XSTR + kc * 32 + kg8];
            a[mt] = cat(*(const s16x4*)p, *(const s16x4*)(p + 4));
        }
        #pragma unroll
        for (int g = 0; g < 3; ++g) {
            const short* pb = &Bs[(g*160 + 16*wv + l15) * BCS + kg8];
            s16x8 bf = cat(*(const s16x4*)pb, *(const s16x4*)(pb + 4));
            #pragma unroll
            for (int mt = 0; mt < 4; ++mt)
                acc[mt][g] = MFMA(a[mt], bf, acc[mt][g]);
        }

        if (kc < 9) {
            __syncthreads();         // all waves done reading slab kc
            stage_slab(Wsl + (kc + 1) * SLAB_SH, Bs, wv, ln);
        }
    }

    // epilogue: wave owns column c of every gate -> in-register gate fusion
    const int c = 16 * wv + l15;     // 0..159
    if (d == 6) {
        float bi = 0.f, bu = 0.f, bo = 0.f;
        if (c < HD) { bi = biuo[c]; bu = biuo[HD + c]; bo = biuo[2*HD + c]; }
        #pragma unroll
        for (int mt = 0; mt < 4; ++mt)
            #pragma unroll
            for (int r = 0; r < 4; ++r) {
                int lcl = local0 + 16*mt + 4*kg + r;
                int b = lcl >> 6, s = lcl & 63;
                size_t nrow = (size_t)b * 127 + 63 + s;
                if (c < HD) {
                    float cn = sig_(acc[mt][0][r] + bi) * tanh_(acc[mt][1][r] + bu);
                    float hn = sig_(acc[mt][2][r] + bo) * tanh_(cn);
                    h_all[nrow * HD + c] = hn;
                    c_ring[((size_t)b * 126 + 62 + s) * 152 + c] = (f16)cn;
                    hb[nrow * 152 + c] = f2bf(hn);
                } else if (c < 152) {
                    hb[nrow * 152 + c] = 0;
                }
            }
    } else if (c < HD) {
        #pragma unroll
        for (int mt = 0; mt < 4; ++mt)
            #pragma unroll
            for (int r = 0; r < 4; ++r) {
                int lcl = local0 + 16*mt + 4*kg + r;
                int b = lcl >> lg, s = lcl & mask;
                f16* ip = iuo_all + ((size_t)b * 63 + start + s) * 456;
                ip[c]       = (f16)acc[mt][0][r];
                ip[152 + c] = (f16)acc[mt][1][r];
                ip[304 + c] = (f16)acc[mt][2][r];
            }
    }
}

// -------- light: per internal level. 32 parents/block, 5 waves x 2 col-triples --------
__global__ __launch_bounds__(LNT, 4)
void lvl_light(const short* __restrict__ Ubf, const short* __restrict__ Fbf,
               const float* __restrict__ biuo, const float* __restrict__ Ufb,
               const f16* __restrict__ iuo_all, f16* __restrict__ c_ring,
               float* __restrict__ h_all, short* __restrict__ hb,
               int start, int lg, int cstart)
{
    __shared__ short chs[2][32][CSTR];
    __shared__ short hts[32][CSTR];
    __shared__ short fgs[5][64][34];

    const int t = threadIdx.x;
    const int wv = t >> 6, ln = t & 63, l15 = ln & 15, kg = ln >> 4;
    const int row0 = blockIdx.x * 32;
    const int mask = (1 << lg) - 1;
    const int ct0 = 16 * (2*wv)     + l15;
    const int ct1 = 16 * (2*wv + 1) + l15;

    for (int idx = t; idx < 64 * 19; idx += LNT) {
        int rw = idx / 19, seg = idx - rw * 19;
        int plane = rw >> 5, lr = rw & 31;
        int row = row0 + lr, b = row >> lg, s = row & mask;
        const short* hp = hb + ((size_t)b*127 + cstart + 2*s + plane) * 152 + seg * 8;
        *(s16x8*)&chs[plane][lr][seg * 8] = *(const s16x8*)hp;
    }
    if (t < 64) {
        int plane = t >> 5, lr = t & 31;
        *(s16x8*)&chs[plane][lr][152] = s16x8{0,0,0,0,0,0,0,0};
    }
    __syncthreads();

    {
        int r = t / 10, sg = t - 10 * (t / 10);
        int k0 = sg * 16;
        s16x8 h0a = *(const s16x8*)&chs[0][r][k0];
        s16x8 h0b = *(const s16x8*)&chs[0][r][k0 + 8];
        s16x8 h1a = *(const s16x8*)&chs[1][r][k0];
        s16x8 h1b = *(const s16x8*)&chs[1][r][k0 + 8];
        s16x8 oa, ob;
        #pragma unroll
        for (int e = 0; e < 8; ++e) {
            oa[e] = f2bf(bf2f(h0a[e]) + bf2f(h1a[e]));
            ob[e] = f2bf(bf2f(h0b[e]) + bf2f(h1b[e]));
        }
        *(s16x8*)&hts[r][k0]     = oa;
        *(s16x8*)&hts[r][k0 + 8] = ob;
    }

    f32x4 facc[4][2] = {};
    #pragma unroll
    for (int kc = 0; kc < 5; ++kc) {
        int ka = kc * 32 + kg * 8;
        s16x8 af[4];
        #pragma unroll
        for (int rt = 0; rt < 4; ++rt) {
            const short* p = &chs[rt >> 1][(rt & 1) * 16 + l15][ka];
            af[rt] = cat(*(const s16x4*)p, *(const s16x4*)(p + 4));
        }
        #pragma unroll
        for (int tt = 0; tt < 2; ++tt) {
            int ct = tt ? ct1 : ct0;
            s16x8 bf = *(const s16x8*)(Fbf + (size_t)ct * 160 + ka);
            #pragma unroll
            for (int rt = 0; rt < 4; ++rt)
                facc[rt][tt] = MFMA(af[rt], bf, facc[rt][tt]);
        }
    }
    #pragma unroll
    for (int tt = 0; tt < 2; ++tt) {
        int ct = tt ? ct1 : ct0;
        float fb_ = (ct < HD) ? Ufb[ct] : 0.0f;
        #pragma unroll
        for (int rt = 0; rt < 4; ++rt)
            #pragma unroll
            for (int r = 0; r < 4; ++r)
                fgs[wv][rt*16 + 4*kg + r][tt*16 + l15] = f2bf(sig_(facc[rt][tt][r] + fb_));
    }
    __syncthreads();

    f32x4 acc[2][2][3] = {};
    #pragma unroll
    for (int kc = 0; kc < 5; ++kc) {
        int ka = kc * 32 + kg * 8;
        s16x8 hs[2];
        #pragma unroll
        for (int mt = 0; mt < 2; ++mt) {
            const short* p = &hts[16*mt + l15][ka];
            hs[mt] = cat(*(const s16x4*)p, *(const s16x4*)(p + 4));
        }
        #pragma unroll
        for (int tt = 0; tt < 2; ++tt) {
            int ct = tt ? ct1 : ct0;
            #pragma unroll
            for (int g = 0; g < 3; ++g) {
                s16x8 bf = *(const s16x8*)(Ubf + (size_t)(g*160 + ct) * 160 + ka);
                #pragma unroll
                for (int mt = 0; mt < 2; ++mt)
                    acc[mt][tt][g] = MFMA(hs[mt], bf, acc[mt][tt][g]);
            }
        }
    }

    #pragma unroll
    for (int tt = 0; tt < 2; ++tt) {
        int c = tt ? ct1 : ct0;
        float bi = 0.f, bu = 0.f, bo = 0.f;
        if (c < HD) { bi = biuo[c]; bu = biuo[HD + c]; bo = biuo[2*HD + c]; }
        #pragma unroll
        for (int mt = 0; mt < 2; ++mt)
            #pragma unroll
            for (int r = 0; r < 4; ++r) {
                int pl = 16*mt + 4*kg + r;
                int row = row0 + pl, b = row >> lg, s = row & mask;
                size_t nrow = (size_t)b*127 + start + s;
                if (c < HD) {
                    const f16* ip = iuo_all + ((size_t)b*63 + start + s) * 456;
                    float ig = (float)ip[c]       + bi + acc[mt][tt][0][r];
                    float ug = (float)ip[152 + c] + bu + acc[mt][tt][1][r];
                    float og = (float)ip[304 + c] + bo + acc[mt][tt][2][r];
                    float f0 = bf2f(fgs[wv][pl][tt*16 + l15]);
                    float f1 = bf2f(fgs[wv][32 + pl][tt*16 + l15]);
                    size_t ci = ((size_t)b*126 + cstart + 2*s - 1) * 152 + c;
                    float c0 = (float)c_ring[ci];
                    float c1 = (float)c_ring[ci + 152];
                    float cn = sig_(ig) * tanh_(ug) + f0*c0 + f1*c1;
                    float hn = sig_(og) * tanh_(cn);
                    h_all[nrow * HD + c] = hn;
                    hb[nrow * 152 + c] = f2bf(hn);
                    if (start > 0)
                        c_ring[((size_t)b*126 + start + s - 1) * 152 + c] = (f16)cn;
                } else if (c < 152) {
                    hb[nrow * 152 + c] = 0;
                }
            }
    }
}

extern "C" void kernel_launch(void* const* d_in, const int* in_sizes, int n_in,
                              void* d_out, int out_size, void* d_ws, size_t ws_size,
                              hipStream_t stream) {
    const float* x    = (const float*)d_in[0];
    const float* Wiuo = (const float*)d_in[1];
    const float* Uiuo = (const float*)d_in[2];
    const float* biuo = (const float*)d_in[3];
    const float* Ufw  = (const float*)d_in[4];
    const float* Ufb  = (const float*)d_in[5];
    float* h = (float*)d_out;

    f16*   c_ring  = (f16*)d_ws;
    short* hb      = (short*)(c_ring + C_N);
    f16*   iuo_all = (f16*)(hb + HB_N);
    short* slabs   = (short*)(iuo_all + IUO_N);
    const short* Wsl = slabs;
    const short* Ubf = slabs + W_SH;
    const short* Fbf = slabs + W_SH + U_SH;

    (void)hipFuncSetAttribute((const void*)big_gemm,
                              hipFuncAttributeMaxDynamicSharedMemorySize, 160 * 1024);

    prep_w<<<(W_SH + U_SH + F_SH + 255) / 256, 256, 0, stream>>>(Wiuo, Uiuo, Ufw, slabs);

    big_gemm<<<8128, GNT, GEMM_LDS, stream>>>(x, Wsl, biuo, h, c_ring, hb, iuo_all);

    for (int d = 5; d >= 0; --d) {
        const int start = (1 << d) - 1, cstart = (1 << (d+1)) - 1;
        lvl_light<<<128 << d, LNT, 0, stream>>>(Ubf, Fbf, biuo, Ufb, iuo_all, c_ring, h, hb,
                                                start, d, cstart);
    }
}

// Round 15
// 1167.087 us; speedup vs baseline: 1.0261x; 1.0261x over previous
//
#include <hip/hip_runtime.h>

typedef float  f32x4  __attribute__((ext_vector_type(4)));
typedef short  s16x8  __attribute__((ext_vector_type(8)));
typedef short  s16x4  __attribute__((ext_vector_type(4)));
typedef _Float16 f16;

namespace {
constexpr int NN = 127, IDIM = 300, HD = 150;
constexpr int GNT = 640;             // gemm: 10 waves; wave wv owns col-triple wv
constexpr int XSTR = 324;            // A stride (shorts): 162 dw -> 2-way banks (free)
constexpr int BCS  = 36;             // B col stride (shorts): 18 dw -> 16-bank spread
constexpr int SLAB_SH = 17408;       // 480*36=17280 + pad = 34 KiB
constexpr int SCH = 34;              // 1-KiB staging chunks per slab (waves 0-3: 4, 4-9: 3)
constexpr int A_SH = 64 * XSTR;      // 20736 shorts
constexpr int GEMM_LDS = (A_SH + 3 * SLAB_SH) * 2;   // 145,920 B -> 1 block/CU
constexpr int LNT = 320;
constexpr int CSTR = 168;            // light chs/hts stride

constexpr int W_SH = 10 * SLAB_SH;   // [kc][col][36]
constexpr int U_SH = 480 * 160;      // plain [col][k]
constexpr int F_SH = 160 * 160;

// ws rings: c f16 [4096][126][152] | hb bf16 [4096][127][152] | iuo f16 [4096][63][456] | slabs
constexpr size_t C_N   = (size_t)4096 * 126 * 152;
constexpr size_t HB_N  = (size_t)4096 * 127 * 152;
constexpr size_t IUO_N = (size_t)4096 * 63 * 456;

__device__ __forceinline__ short f2bf(float f) {
    union { __bf16 b; short s; } u; u.b = (__bf16)f; return u.s;
}
__device__ __forceinline__ float bf2f(short s) {
    union { float f; unsigned u; } v; v.u = ((unsigned)(unsigned short)s) << 16; return v.f;
}
__device__ __forceinline__ float sig_(float x)  { return 1.0f / (1.0f + __expf(-x)); }
__device__ __forceinline__ float tanh_(float x) { float e = __expf(2.0f * x); return 1.0f - 2.0f / (e + 1.0f); }
__device__ __forceinline__ s16x4 cvt4(float a,float b,float c,float d) {
    return s16x4{ f2bf(a), f2bf(b), f2bf(c), f2bf(d) };
}
__device__ __forceinline__ s16x8 cat(s16x4 lo, s16x4 hi) {
    return __builtin_shufflevector(lo, hi, 0,1,2,3,4,5,6,7);
}
__device__ __forceinline__ f32x4 MFMA(s16x8 a, s16x8 b, f32x4 c) {
    return __builtin_amdgcn_mfma_f32_16x16x32_bf16(a, b, c, 0, 0, 0);
}
typedef const __attribute__((address_space(1))) unsigned int* gp_t;
typedef __attribute__((address_space(3))) unsigned int* lp_t;
__device__ __forceinline__ void stage_slab(const short* g, short* l, int wv, int ln) {
    const char* gb = (const char*)g;
    char* lb = (char*)l;
    for (int c = wv; c < SCH; c += 10)
        __builtin_amdgcn_global_load_lds((gp_t)(gb + c * 1024 + ln * 16),
                                         (lp_t)(lb + c * 1024 + ln * 16), 16, 0, 0);
}
} // namespace

// -------- one-time weight prep: W -> 10 K-chunk slabs [480][36]; U,F plain [col][160] --------
__global__ __launch_bounds__(256)
void prep_w(const float* __restrict__ Wiuo, const float* __restrict__ Uiuo,
            const float* __restrict__ Ufw, short* __restrict__ dst) {
    int i = blockIdx.x * 256 + threadIdx.x;
    short v = 0;
    if (i < W_SH) {
        int kc = i / SLAB_SH, r = i - kc * SLAB_SH;
        if (r < 480 * BCS) {
            int col = r / BCS, j = r - col * BCS;
            int g = col / 160, cp = col - g * 160, k = kc * 32 + j;
            if (cp < HD && j < 32 && k < IDIM) v = f2bf(Wiuo[(size_t)(g*HD + cp)*IDIM + k]);
        }
        dst[i] = v;
    } else if (i < W_SH + U_SH) {
        int q = i - W_SH;
        int col = q / 160, k = q - col * 160;
        int g = col / 160, cp = col - g * 160;
        if (cp < HD && k < HD) v = f2bf(Uiuo[(size_t)(g*HD + cp)*HD + k]);
        dst[i] = v;
    } else if (i < W_SH + U_SH + F_SH) {
        int q = i - W_SH - U_SH;
        int col = q / 160, k = q - col * 160;
        if (col < HD && k < HD) v = f2bf(Ufw[(size_t)col*HD + k]);
        dst[i] = v;
    }
}

// -------- merged projection GEMM: A prologue-staged, 3-slab ring, counted-vmcnt (T4) --------
// Depth-2 prefetch: slab kc's DMA gets two full compute phases; slab kc+1 stays in
// flight ACROSS the barrier (never vmcnt(0) in the main loop; m218 mechanism).
// MFMA maps: A row=lane&15, B col=lane&15 (shared lane->k); C/D col=lane&15, row=4*(lane>>4)+reg.
__global__ __launch_bounds__(GNT)
void big_gemm(const float* __restrict__ x, const short* __restrict__ Wsl,
              const float* __restrict__ biuo, float* __restrict__ h_all,
              f16* __restrict__ c_ring, short* __restrict__ hb,
              f16* __restrict__ iuo_all)
{
    extern __shared__ short smem[];
    short* As = smem;                // [64][324]
    short* Bbuf = smem + A_SH;       // [3][SLAB_SH]

    const int t = threadIdx.x;
    const int wv = t >> 6, ln = t & 63, l15 = ln & 15, kg = ln >> 4;
    const int kg8 = kg * 8;
    const int row0 = blockIdx.x * 64;

    int d = 6;
    #pragma unroll
    for (int dd = 0; dd <= 5; ++dd)
        if (row0 >= 4096 * (128 - (2 << dd))) { d = dd; break; }
    const int base = 4096 * (128 - (2 << d));
    const int lg = d, mask = (1 << lg) - 1, start = (1 << lg) - 1;
    const int local0 = row0 - base;

    // prologue: issue slab 0, stage A (coalesced float4 -> bf16 quads), issue slab 1
    stage_slab(Wsl, Bbuf, wv, ln);
    {
        constexpr int NQ = XSTR / 4;     // 81 quads/row
        for (int u = t; u < 64 * NQ; u += GNT) {
            int row = u / NQ, q = u - row * NQ;
            int k0 = q * 4;
            int lcl = local0 + row, b = lcl >> lg, s = lcl & mask;
            s16x4 v = {0,0,0,0};
            if (k0 + 4 <= IDIM) {
                float4 f = *(const float4*)(x + ((size_t)b * NN + start + s) * IDIM + k0);
                v = cvt4(f.x, f.y, f.z, f.w);
            }
            *(s16x4*)&As[row * XSTR + k0] = v;
        }
    }
    stage_slab(Wsl + SLAB_SH, Bbuf + SLAB_SH, wv, ln);

    f32x4 acc[4][3] = {};            // [row-tile mt][gate g]
    #pragma unroll
    for (int kc = 0; kc < 10; ++kc) {
        // own stage(kc) loads done; stage(kc+1)'s (newest nw) may stay in flight.
        // lgkmcnt(0): prologue ds_writes visible before first barrier (cheap later).
        if (kc == 9) {
            asm volatile("s_waitcnt vmcnt(0) lgkmcnt(0)" ::: "memory");
        } else if (wv < 4) {
            asm volatile("s_waitcnt vmcnt(4) lgkmcnt(0)" ::: "memory");
        } else {
            asm volatile("s_waitcnt vmcnt(3) lgkmcnt(0)" ::: "memory");
        }
        __builtin_amdgcn_sched_barrier(0);
        __builtin_amdgcn_s_barrier();
        __builtin_amdgcn_sched_barrier(0);

        if (kc < 8)   // buffer (kc+2)%3's readers finished before this barrier
            stage_slab(Wsl + (kc + 2) * SLAB_SH, Bbuf + ((kc + 2) % 3) * SLAB_SH, wv, ln);

        const short* Bc = Bbuf + (kc % 3) * SLAB_SH;
        s16x8 a[4];
        #pragma unroll
        for (int mt = 0; mt < 4; ++mt) {
            const short* p = &As[(16*mt + l15) * XSTR + kc * 32 + kg8];
            a[mt] = cat(*(const s16x4*)p, *(const s16x4*)(p + 4));
        }
        #pragma unroll
        for (int g = 0; g < 3; ++g) {
            const short* pb = &Bc[(g*160 + 16*wv + l15) * BCS + kg8];
            s16x8 bf = cat(*(const s16x4*)pb, *(const s16x4*)(pb + 4));
            #pragma unroll
            for (int mt = 0; mt < 4; ++mt)
                acc[mt][g] = MFMA(a[mt], bf, acc[mt][g]);
        }
    }

    // epilogue: wave owns column c of every gate -> in-register gate fusion
    const int c = 16 * wv + l15;     // 0..159
    if (d == 6) {
        float bi = 0.f, bu = 0.f, bo = 0.f;
        if (c < HD) { bi = biuo[c]; bu = biuo[HD + c]; bo = biuo[2*HD + c]; }
        #pragma unroll
        for (int mt = 0; mt < 4; ++mt)
            #pragma unroll
            for (int r = 0; r < 4; ++r) {
                int lcl = local0 + 16*mt + 4*kg + r;
                int b = lcl >> 6, s = lcl & 63;
                size_t nrow = (size_t)b * 127 + 63 + s;
                if (c < HD) {
                    float cn = sig_(acc[mt][0][r] + bi) * tanh_(acc[mt][1][r] + bu);
                    float hn = sig_(acc[mt][2][r] + bo) * tanh_(cn);
                    h_all[nrow * HD + c] = hn;
                    c_ring[((size_t)b * 126 + 62 + s) * 152 + c] = (f16)cn;
                    hb[nrow * 152 + c] = f2bf(hn);
                } else if (c < 152) {
                    hb[nrow * 152 + c] = 0;
                }
            }
    } else if (c < HD) {
        #pragma unroll
        for (int mt = 0; mt < 4; ++mt)
            #pragma unroll
            for (int r = 0; r < 4; ++r) {
                int lcl = local0 + 16*mt + 4*kg + r;
                int b = lcl >> lg, s = lcl & mask;
                f16* ip = iuo_all + ((size_t)b * 63 + start + s) * 456;
                ip[c]       = (f16)acc[mt][0][r];
                ip[152 + c] = (f16)acc[mt][1][r];
                ip[304 + c] = (f16)acc[mt][2][r];
            }
    }
}

// -------- light: per internal level. 32 parents/block, 5 waves x 2 col-triples --------
__global__ __launch_bounds__(LNT, 4)
void lvl_light(const short* __restrict__ Ubf, const short* __restrict__ Fbf,
               const float* __restrict__ biuo, const float* __restrict__ Ufb,
               const f16* __restrict__ iuo_all, f16* __restrict__ c_ring,
               float* __restrict__ h_all, short* __restrict__ hb,
               int start, int lg, int cstart)
{
    __shared__ short chs[2][32][CSTR];
    __shared__ short hts[32][CSTR];
    __shared__ short fgs[5][64][34];

    const int t = threadIdx.x;
    const int wv = t >> 6, ln = t & 63, l15 = ln & 15, kg = ln >> 4;
    const int row0 = blockIdx.x * 32;
    const int mask = (1 << lg) - 1;
    const int ct0 = 16 * (2*wv)     + l15;
    const int ct1 = 16 * (2*wv + 1) + l15;

    for (int idx = t; idx < 64 * 19; idx += LNT) {
        int rw = idx / 19, seg = idx - rw * 19;
        int plane = rw >> 5, lr = rw & 31;
        int row = row0 + lr, b = row >> lg, s = row & mask;
        const short* hp = hb + ((size_t)b*127 + cstart + 2*s + plane) * 152 + seg * 8;
        *(s16x8*)&chs[plane][lr][seg * 8] = *(const s16x8*)hp;
    }
    if (t < 64) {
        int plane = t >> 5, lr = t & 31;
        *(s16x8*)&chs[plane][lr][152] = s16x8{0,0,0,0,0,0,0,0};
    }
    __syncthreads();

    {
        int r = t / 10, sg = t - 10 * (t / 10);
        int k0 = sg * 16;
        s16x8 h0a = *(const s16x8*)&chs[0][r][k0];
        s16x8 h0b = *(const s16x8*)&chs[0][r][k0 + 8];
        s16x8 h1a = *(const s16x8*)&chs[1][r][k0];
        s16x8 h1b = *(const s16x8*)&chs[1][r][k0 + 8];
        s16x8 oa, ob;
        #pragma unroll
        for (int e = 0; e < 8; ++e) {
            oa[e] = f2bf(bf2f(h0a[e]) + bf2f(h1a[e]));
            ob[e] = f2bf(bf2f(h0b[e]) + bf2f(h1b[e]));
        }
        *(s16x8*)&hts[r][k0]     = oa;
        *(s16x8*)&hts[r][k0 + 8] = ob;
    }

    f32x4 facc[4][2] = {};
    #pragma unroll
    for (int kc = 0; kc < 5; ++kc) {
        int ka = kc * 32 + kg * 8;
        s16x8 af[4];
        #pragma unroll
        for (int rt = 0; rt < 4; ++rt) {
            const short* p = &chs[rt >> 1][(rt & 1) * 16 + l15][ka];
            af[rt] = cat(*(const s16x4*)p, *(const s16x4*)(p + 4));
        }
        #pragma unroll
        for (int tt = 0; tt < 2; ++tt) {
            int ct = tt ? ct1 : ct0;
            s16x8 bf = *(const s16x8*)(Fbf + (size_t)ct * 160 + ka);
            #pragma unroll
            for (int rt = 0; rt < 4; ++rt)
                facc[rt][tt] = MFMA(af[rt], bf, facc[rt][tt]);
        }
    }
    #pragma unroll
    for (int tt = 0; tt < 2; ++tt) {
        int ct = tt ? ct1 : ct0;
        float fb_ = (ct < HD) ? Ufb[ct] : 0.0f;
        #pragma unroll
        for (int rt = 0; rt < 4; ++rt)
            #pragma unroll
            for (int r = 0; r < 4; ++r)
                fgs[wv][rt*16 + 4*kg + r][tt*16 + l15] = f2bf(sig_(facc[rt][tt][r] + fb_));
    }
    __syncthreads();

    f32x4 acc[2][2][3] = {};
    #pragma unroll
    for (int kc = 0; kc < 5; ++kc) {
        int ka = kc * 32 + kg * 8;
        s16x8 hs[2];
        #pragma unroll
        for (int mt = 0; mt < 2; ++mt) {
            const short* p = &hts[16*mt + l15][ka];
            hs[mt] = cat(*(const s16x4*)p, *(const s16x4*)(p + 4));
        }
        #pragma unroll
        for (int tt = 0; tt < 2; ++tt) {
            int ct = tt ? ct1 : ct0;
            #pragma unroll
            for (int g = 0; g < 3; ++g) {
                s16x8 bf = *(const s16x8*)(Ubf + (size_t)(g*160 + ct) * 160 + ka);
                #pragma unroll
                for (int mt = 0; mt < 2; ++mt)
                    acc[mt][tt][g] = MFMA(hs[mt], bf, acc[mt][tt][g]);
            }
        }
    }

    #pragma unroll
    for (int tt = 0; tt < 2; ++tt) {
        int c = tt ? ct1 : ct0;
        float bi = 0.f, bu = 0.f, bo = 0.f;
        if (c < HD) { bi = biuo[c]; bu = biuo[HD + c]; bo = biuo[2*HD + c]; }
        #pragma unroll
        for (int mt = 0; mt < 2; ++mt)
            #pragma unroll
            for (int r = 0; r < 4; ++r) {
                int pl = 16*mt + 4*kg + r;
                int row = row0 + pl, b = row >> lg, s = row & mask;
                size_t nrow = (size_t)b*127 + start + s;
                if (c < HD) {
                    const f16* ip = iuo_all + ((size_t)b*63 + start + s) * 456;
                    float ig = (float)ip[c]       + bi + acc[mt][tt][0][r];
                    float ug = (float)ip[152 + c] + bu + acc[mt][tt][1][r];
                    float og = (float)ip[304 + c] + bo + acc[mt][tt][2][r];
                    float f0 = bf2f(fgs[wv][pl][tt*16 + l15]);
                    float f1 = bf2f(fgs[wv][32 + pl][tt*16 + l15]);
                    size_t ci = ((size_t)b*126 + cstart + 2*s - 1) * 152 + c;
                    float c0 = (float)c_ring[ci];
                    float c1 = (float)c_ring[ci + 152];
                    float cn = sig_(ig) * tanh_(ug) + f0*c0 + f1*c1;
                    float hn = sig_(og) * tanh_(cn);
                    h_all[nrow * HD + c] = hn;
                    hb[nrow * 152 + c] = f2bf(hn);
                    if (start > 0)
                        c_ring[((size_t)b*126 + start + s - 1) * 152 + c] = (f16)cn;
                } else if (c < 152) {
                    hb[nrow * 152 + c] = 0;
                }
            }
    }
}

extern "C" void kernel_launch(void* const* d_in, const int* in_sizes, int n_in,
                              void* d_out, int out_size, void* d_ws, size_t ws_size,
                              hipStream_t stream) {
    const float* x    = (const float*)d_in[0];
    const float* Wiuo = (const float*)d_in[1];
    const float* Uiuo = (const float*)d_in[2];
    const float* biuo = (const float*)d_in[3];
    const float* Ufw  = (const float*)d_in[4];
    const float* Ufb  = (const float*)d_in[5];
    float* h = (float*)d_out;

    f16*   c_ring  = (f16*)d_ws;
    short* hb      = (short*)(c_ring + C_N);
    f16*   iuo_all = (f16*)(hb + HB_N);
    short* slabs   = (short*)(iuo_all + IUO_N);
    const short* Wsl = slabs;
    const short* Ubf = slabs + W_SH;
    const short* Fbf = slabs + W_SH + U_SH;

    (void)hipFuncSetAttribute((const void*)big_gemm,
                              hipFuncAttributeMaxDynamicSharedMemorySize, 160 * 1024);

    prep_w<<<(W_SH + U_SH + F_SH + 255) / 256, 256, 0, stream>>>(Wiuo, Uiuo, Ufw, slabs);

    big_gemm<<<8128, GNT, GEMM_LDS, stream>>>(x, Wsl, biuo, h, c_ring, hb, iuo_all);

    for (int d = 5; d >= 0; --d) {
        const int start = (1 << d) - 1, cstart = (1 << (d+1)) - 1;
        lvl_light<<<128 << d, LNT, 0, stream>>>(Ubf, Fbf, biuo, Ufb, iuo_all, c_ring, h, hb,
                                                start, d, cstart);
    }
}